// Round 11
// baseline (367.074 us; speedup 1.0000x reference)
//
#include <hip/hip_runtime.h>
#include <hip/hip_cooperative_groups.h>
#include <hip/hip_fp16.h>
#include <math.h>

typedef _Float16 f16;
typedef f16 f16x2 __attribute__((ext_vector_type(2)));
typedef f16 f16x4 __attribute__((ext_vector_type(4)));
typedef f16 f16x8 __attribute__((ext_vector_type(8)));
typedef float f32x4_t __attribute__((ext_vector_type(4)));

__device__ __forceinline__ float sigmoidf(float x) {
  return 1.0f / (1.0f + __expf(-x));
}

// direct-to-LDS 16B copy: LDS dest = wave-uniform base + lane*16
#define GLDS16(gp, lp)                                                     \
  __builtin_amdgcn_global_load_lds(                                        \
      (const __attribute__((address_space(1))) void*)(gp),                 \
      (__attribute__((address_space(3))) void*)(lp), 16, 0, 0)

__global__ void zero_ints(int* __restrict__ p, int n) {
  int i = blockIdx.x * blockDim.x + threadIdx.x;
  if (i < n) p[i] = 0;
}

// ===========================================================================
// Cooperative CSR build + prep (N <= 65536, NB <= 256): ONE kernel.
//   phase 1 : per-block edge-chunk hist (LDS) + records to regs; weight
//             transpose (blocks 0..127); P0 = [nf|H] f16 pack (grid-stride)
//   sync -> phase 2: block 0 scans bucket counts -> bbases, gcurP
//   sync -> phase 3: partition (one global reserve per block-bucket,
//                    LDS counting-scatter, bucket-ordered coalesced flush)
//   sync -> phase 4: per-bucket counting sort -> eidx (u16), off
// ===========================================================================
__global__ __launch_bounds__(256) void csr_prep_coop(
    const int* __restrict__ src, const int* __restrict__ dst, int E, int N,
    int NB, int nhb, int* __restrict__ hrows, int* __restrict__ bbases,
    int* __restrict__ gcurP, unsigned int* __restrict__ bin,
    unsigned short* __restrict__ eidx, int* __restrict__ off,
    const float* __restrict__ Wm, const float* __restrict__ Wz,
    const float* __restrict__ Wr, const float* __restrict__ Wh,
    f16* __restrict__ WtM, f16* __restrict__ WtZR, f16* __restrict__ WtH,
    const float* __restrict__ nf, const float* __restrict__ H,
    f16* __restrict__ P0) {
  cooperative_groups::grid_group grid = cooperative_groups::this_grid();
  const int b = blockIdx.x, tid = threadIdx.x;
  __shared__ int h[256];
  __shared__ int bofs[257];
  __shared__ int gbase[256];
  __shared__ int wsum4[4];
  __shared__ unsigned int recs[4096];
  __shared__ unsigned short srt[8192];
  __shared__ int lofs[256];
  __shared__ int cnt2s[256];
  __shared__ float tile[32][33];

  // ---- phase 1: hist + record load ----
  unsigned int rec[16];
  int bk[16];
  h[tid] = 0;
  __syncthreads();
  if (b < nhb) {
    const int base = b * 4096;
    #pragma unroll
    for (int k = 0; k < 16; ++k) {
      int e = base + tid + k * 256;
      if (e < E) {
        int d = dst[e];
        rec[k] = (unsigned int)(src[e] & 0xFFFF) | ((unsigned int)(d & 255) << 16);
        bk[k] = d >> 8;
        atomicAdd(&h[bk[k]], 1);
      } else {
        bk[k] = -1;
      }
    }
  } else {
    #pragma unroll
    for (int k = 0; k < 16; ++k) bk[k] = -1;
  }
  __syncthreads();
  if (b < nhb) hrows[(size_t)b * 256 + tid] = h[tid];

  // ---- phase 1b: weight transpose (blocks 0..127) ----
  if (b < 128) {
    const int x = b & 7, y = (b >> 3) & 3, z = b >> 5;
    const float* W;
    f16* O;
    int K;
    switch (z) {
      case 0: W = Wm; O = WtM; K = 128; break;
      case 1: W = Wz; O = WtZR; K = 256; break;
      case 2: W = Wr; O = WtZR + 128 * 256; K = 256; break;
      default: W = Wh; O = WtH; K = 256; break;
    }
    int bkk = x * 32, bn = y * 32;
    if (bkk < K) {
      int tx = tid & 31, ty = tid >> 5;
      #pragma unroll
      for (int i = 0; i < 4; ++i)
        tile[ty + 8 * i][tx] = W[(size_t)(bkk + ty + 8 * i) * 128 + bn + tx];
      __syncthreads();
      #pragma unroll
      for (int i = 0; i < 4; ++i)
        O[(size_t)(bn + ty + 8 * i) * K + bkk + tx] = (f16)tile[tx][ty + 8 * i];
    }
  }
  // ---- phase 1c: pack P0 (grid-stride, 1 node/wave) ----
  {
    const int wv = tid >> 6, lane = tid & 63;
    const float* S = (lane < 32) ? nf : H;
    const int c = (lane & 31) * 4;
    const int coloff = (lane < 32) ? 0 : 128;
    for (int w = b * 4 + wv; w < N; w += gridDim.x * 4) {
      float4 u = *(const float4*)&S[(size_t)w * 128 + c];
      f16x4 o = {(f16)u.x, (f16)u.y, (f16)u.z, (f16)u.w};
      *(f16x4*)&P0[(size_t)w * 256 + coloff + c] = o;
    }
  }

  grid.sync();

  // ---- phase 2: bucket scan (block 0) ----
  if (b == 0) {
    int v = 0;
    for (int b2 = 0; b2 < nhb; ++b2) v += hrows[(size_t)b2 * 256 + tid];
    if (tid >= NB) v = 0;
    const int lane = tid & 63, wid = tid >> 6;
    int x = v;
    #pragma unroll
    for (int d = 1; d < 64; d <<= 1) { int y = __shfl_up(x, d); if (lane >= d) x += y; }
    if (lane == 63) wsum4[wid] = x;
    __syncthreads();
    if (wid == 0 && lane < 4) {
      int wsv = wsum4[lane];
      #pragma unroll
      for (int d = 1; d < 4; d <<= 1) { int y = __shfl_up(wsv, d); if (lane >= d) wsv += y; }
      wsum4[lane] = wsv;
    }
    __syncthreads();
    int excl = x - v + (wid ? wsum4[wid - 1] : 0);
    if (tid < NB) { bbases[tid] = excl; gcurP[tid * 16] = excl; }
    if (tid == NB - 1) bbases[NB] = excl + v;
  }

  grid.sync();

  // ---- phase 3: partition (h still holds this block's hist) ----
  if (b < nhb) {
    if (tid < 64) {
      int l = tid;
      int v0 = h[4 * l], v1 = h[4 * l + 1], v2 = h[4 * l + 2], v3 = h[4 * l + 3];
      int s1 = v0 + v1, s2 = s1 + v2, t = s2 + v3;
      int x = t;
      #pragma unroll
      for (int d = 1; d < 64; d <<= 1) { int y = __shfl_up(x, d); if (l >= d) x += y; }
      int basex = x - t;
      bofs[4 * l] = basex;
      bofs[4 * l + 1] = basex + v0;
      bofs[4 * l + 2] = basex + s1;
      bofs[4 * l + 3] = basex + s2;
      if (l == 63) bofs[256] = x;
    }
    __syncthreads();
    if (tid < NB && h[tid] > 0)
      gbase[tid] = atomicAdd(&gcurP[tid * 16], h[tid]);
    __syncthreads();
    h[tid] = bofs[tid];          // reuse h as local cursor
    __syncthreads();
    #pragma unroll
    for (int k = 0; k < 16; ++k) {
      if (bk[k] >= 0) {
        int p = atomicAdd(&h[bk[k]], 1);
        recs[p] = rec[k];
      }
    }
    __syncthreads();
    const int total = bofs[256];
    for (int i = tid; i < total; i += 256) {
      int lo = 0, hi = 256;
      #pragma unroll
      for (int s = 0; s < 8; ++s) {
        int mid = (lo + hi) >> 1;
        if (bofs[mid] <= i) lo = mid; else hi = mid;
      }
      bin[gbase[lo] + (i - bofs[lo])] = recs[i];
    }
  }

  grid.sync();

  // ---- phase 4: per-bucket counting sort ----
  if (b < NB) {
    const int bb = bbases[b], be = bbases[b + 1];
    const int cntb = be - bb;
    const int d0 = b << 8;
    const int ndst = min(256, N - d0);
    h[tid] = 0;
    cnt2s[tid] = 0;
    __syncthreads();
    for (int i = bb + tid; i < be; i += 256)
      atomicAdd(&h[(bin[i] >> 16) & 255], 1);
    __syncthreads();
    if (tid < 64) {
      int l = tid;
      int v0 = h[4 * l], v1 = h[4 * l + 1], v2 = h[4 * l + 2], v3 = h[4 * l + 3];
      int s1 = v0 + v1, s2 = s1 + v2, t = s2 + v3;
      int x = t;
      #pragma unroll
      for (int d = 1; d < 64; d <<= 1) { int y = __shfl_up(x, d); if (l >= d) x += y; }
      int basex = x - t;
      lofs[4 * l] = basex;
      lofs[4 * l + 1] = basex + v0;
      lofs[4 * l + 2] = basex + s1;
      lofs[4 * l + 3] = basex + s2;
    }
    __syncthreads();
    if (tid < ndst) off[d0 + tid] = bb + lofs[tid];
    if (b == NB - 1 && tid == 0) off[N] = be;
    if (cntb <= 8192) {
      for (int i = bb + tid; i < be; i += 256) {
        unsigned int r = bin[i];
        int ld = (r >> 16) & 255;
        int p = lofs[ld] + atomicAdd(&cnt2s[ld], 1);
        srt[p] = (unsigned short)(r & 0xFFFF);
      }
      __syncthreads();
      for (int i = tid; i < cntb; i += 256) eidx[bb + i] = srt[i];
    } else {
      for (int i = bb + tid; i < be; i += 256) {
        unsigned int r = bin[i];
        int ld = (r >> 16) & 255;
        int p = bb + lofs[ld] + atomicAdd(&cnt2s[ld], 1);
        eidx[p] = (unsigned short)(r & 0xFFFF);
      }
    }
  }
}

// ===========================================================================
// Fallback CSR build v4 (non-cooperative), N <= 65536
// ===========================================================================
__global__ __launch_bounds__(256) void bucket_hist2(const int* __restrict__ dst,
                                                    int* __restrict__ hrows, int E) {
  __shared__ int h[256];
  h[threadIdx.x] = 0;
  __syncthreads();
  int base = blockIdx.x * 4096;
  int lim = min(base + 4096, E);
  for (int e = base + threadIdx.x; e < lim; e += 256)
    atomicAdd(&h[dst[e] >> 8], 1);
  __syncthreads();
  hrows[blockIdx.x * 256 + threadIdx.x] = h[threadIdx.x];
}

__global__ __launch_bounds__(256) void bucket_scan2(const int* __restrict__ hrows,
                                                    int nhb, int* __restrict__ bbases,
                                                    int* __restrict__ gcurP, int NB) {
  __shared__ int wsum[4];
  const int tid = threadIdx.x, lane = tid & 63, wid = tid >> 6;
  int v = 0;
  for (int b = 0; b < nhb; ++b) v += hrows[b * 256 + tid];
  if (tid >= NB) v = 0;
  int x = v;
  #pragma unroll
  for (int d = 1; d < 64; d <<= 1) { int y = __shfl_up(x, d); if (lane >= d) x += y; }
  if (lane == 63) wsum[wid] = x;
  __syncthreads();
  if (wid == 0 && lane < 4) {
    int ws = wsum[lane];
    #pragma unroll
    for (int d = 1; d < 4; d <<= 1) { int y = __shfl_up(ws, d); if (lane >= d) ws += y; }
    wsum[lane] = ws;
  }
  __syncthreads();
  int excl = x - v + (wid ? wsum[wid - 1] : 0);
  if (tid < NB) { bbases[tid] = excl; gcurP[tid * 16] = excl; }
  if (tid == NB - 1) bbases[NB] = excl + v;
}

__global__ __launch_bounds__(256) void partition_v2(const int* __restrict__ src,
                                                    const int* __restrict__ dst,
                                                    int* __restrict__ gcurP,
                                                    unsigned int* __restrict__ bin,
                                                    int E, int NB) {
  __shared__ int bhist[256];
  __shared__ int bofs[257];
  __shared__ int gbase[256];
  __shared__ unsigned int recs[4096];
  const int tid = threadIdx.x;
  const int base = blockIdx.x * 4096;
  bhist[tid] = 0;
  __syncthreads();
  unsigned int rec[16];
  int bk[16];
  #pragma unroll
  for (int k = 0; k < 16; ++k) {
    int e = base + tid + k * 256;
    if (e < E) {
      int d = dst[e];
      rec[k] = (unsigned int)(src[e] & 0xFFFF) | ((unsigned int)(d & 255) << 16);
      bk[k] = d >> 8;
      atomicAdd(&bhist[bk[k]], 1);
    } else {
      bk[k] = -1;
    }
  }
  __syncthreads();
  if (tid < 64) {
    int l = tid;
    int v0 = bhist[4 * l], v1 = bhist[4 * l + 1];
    int v2 = bhist[4 * l + 2], v3 = bhist[4 * l + 3];
    int s1 = v0 + v1, s2 = s1 + v2, t = s2 + v3;
    int x = t;
    #pragma unroll
    for (int d = 1; d < 64; d <<= 1) { int y = __shfl_up(x, d); if (l >= d) x += y; }
    int basex = x - t;
    bofs[4 * l] = basex;
    bofs[4 * l + 1] = basex + v0;
    bofs[4 * l + 2] = basex + s1;
    bofs[4 * l + 3] = basex + s2;
    if (l == 63) bofs[256] = x;
  }
  __syncthreads();
  if (tid < NB && bhist[tid] > 0)
    gbase[tid] = atomicAdd(&gcurP[tid * 16], bhist[tid]);
  __syncthreads();
  bhist[tid] = bofs[tid];
  __syncthreads();
  #pragma unroll
  for (int k = 0; k < 16; ++k) {
    if (bk[k] >= 0) {
      int p = atomicAdd(&bhist[bk[k]], 1);
      recs[p] = rec[k];
    }
  }
  __syncthreads();
  const int total = bofs[256];
  for (int i = tid; i < total; i += 256) {
    int lo = 0, hi = 256;
    #pragma unroll
    for (int s = 0; s < 8; ++s) {
      int mid = (lo + hi) >> 1;
      if (bofs[mid] <= i) lo = mid; else hi = mid;
    }
    bin[gbase[lo] + (i - bofs[lo])] = recs[i];
  }
}

__global__ __launch_bounds__(256) void bucket_sort(const unsigned int* __restrict__ bin,
                                                   const int* __restrict__ bbases,
                                                   unsigned short* __restrict__ eidx,
                                                   int* __restrict__ off,
                                                   int N, int NB) {
  const int b = blockIdx.x;
  const int bb = bbases[b], be = bbases[b + 1];
  const int cntb = be - bb;
  const int d0 = b << 8;
  const int ndst = min(256, N - d0);
  __shared__ int hist[256];
  __shared__ int lofs[256];
  __shared__ int cnt2[256];
  __shared__ unsigned short srt[8192];
  const int tid = threadIdx.x;
  hist[tid] = 0;
  cnt2[tid] = 0;
  __syncthreads();
  for (int i = bb + tid; i < be; i += 256)
    atomicAdd(&hist[(bin[i] >> 16) & 255], 1);
  __syncthreads();
  if (tid < 64) {
    int l = tid;
    int v0 = hist[4 * l], v1 = hist[4 * l + 1], v2 = hist[4 * l + 2], v3 = hist[4 * l + 3];
    int s1 = v0 + v1, s2 = s1 + v2, t = s2 + v3;
    int x = t;
    #pragma unroll
    for (int d = 1; d < 64; d <<= 1) { int y = __shfl_up(x, d); if (l >= d) x += y; }
    int basex = x - t;
    lofs[4 * l] = basex;
    lofs[4 * l + 1] = basex + v0;
    lofs[4 * l + 2] = basex + s1;
    lofs[4 * l + 3] = basex + s2;
  }
  __syncthreads();
  if (tid < ndst) off[d0 + tid] = bb + lofs[tid];
  if (b == NB - 1 && tid == 0) off[N] = be;
  if (cntb <= 8192) {
    for (int i = bb + tid; i < be; i += 256) {
      unsigned int r = bin[i];
      int ld = (r >> 16) & 255;
      int p = lofs[ld] + atomicAdd(&cnt2[ld], 1);
      srt[p] = (unsigned short)(r & 0xFFFF);
    }
    __syncthreads();
    for (int i = tid; i < cntb; i += 256) eidx[bb + i] = srt[i];
  } else {
    for (int i = bb + tid; i < be; i += 256) {
      unsigned int r = bin[i];
      int ld = (r >> 16) & 255;
      int p = bb + lofs[ld] + atomicAdd(&cnt2[ld], 1);
      eidx[p] = (unsigned short)(r & 0xFFFF);
    }
  }
}

// ===========================================================================
// Fallback CSR build (N > 65536)
// ===========================================================================
__global__ void count_kernel(const int* __restrict__ dst, int* __restrict__ cnt, int E) {
  int base = (blockIdx.x * blockDim.x + threadIdx.x) * 4;
  if (base + 3 < E) {
    int4 d = *(const int4*)&dst[base];
    atomicAdd(&cnt[d.x], 1);
    atomicAdd(&cnt[d.y], 1);
    atomicAdd(&cnt[d.z], 1);
    atomicAdd(&cnt[d.w], 1);
  } else {
    for (int e = base; e < E; ++e) atomicAdd(&cnt[dst[e]], 1);
  }
}

__global__ __launch_bounds__(1024) void scan_local(const int* __restrict__ cnt,
                                                   int* __restrict__ off,
                                                   int* __restrict__ psum, int n) {
  __shared__ int wsum[16];
  const int tid = threadIdx.x, lane = tid & 63, wid = tid >> 6;
  int i = blockIdx.x * 1024 + tid;
  int v = (i < n) ? cnt[i] : 0;
  int x = v;
  #pragma unroll
  for (int d = 1; d < 64; d <<= 1) { int y = __shfl_up(x, d); if (lane >= d) x += y; }
  if (lane == 63) wsum[wid] = x;
  __syncthreads();
  if (wid == 0) {
    int ws = (lane < 16) ? wsum[lane] : 0;
    #pragma unroll
    for (int d = 1; d < 16; d <<= 1) { int y = __shfl_up(ws, d); if (lane >= d) ws += y; }
    if (lane < 16) wsum[lane] = ws;
  }
  __syncthreads();
  int excl = x - v + (wid ? wsum[wid - 1] : 0);
  if (i < n) off[i] = excl;
  if (tid == 1023) psum[blockIdx.x] = wsum[15];
}

__global__ __launch_bounds__(1024) void scan_carry(int* __restrict__ psum,
                                                   int* __restrict__ off,
                                                   int* __restrict__ cur, int nb, int n) {
  __shared__ int wsum[16];
  const int tid = threadIdx.x, lane = tid & 63, wid = tid >> 6;
  int v = (tid < nb) ? psum[tid] : 0;
  int x = v;
  #pragma unroll
  for (int d = 1; d < 64; d <<= 1) { int y = __shfl_up(x, d); if (lane >= d) x += y; }
  if (lane == 63) wsum[wid] = x;
  __syncthreads();
  if (wid == 0) {
    int ws = (lane < 16) ? wsum[lane] : 0;
    #pragma unroll
    for (int d = 1; d < 16; d <<= 1) { int y = __shfl_up(ws, d); if (lane >= d) ws += y; }
    if (lane < 16) wsum[lane] = ws;
  }
  __syncthreads();
  int excl = x - v + (wid ? wsum[wid - 1] : 0);
  if (tid < nb) psum[tid] = excl;
  if (tid == 1023) { off[n] = wsum[15]; cur[n] = wsum[15]; }
}

__global__ __launch_bounds__(1024) void scan_add(int* __restrict__ off, int* __restrict__ cur,
                                                 const int* __restrict__ psum, int n) {
  int i = blockIdx.x * 1024 + threadIdx.x;
  if (i < n) {
    int t = off[i] + psum[blockIdx.x];
    off[i] = t;
    cur[i] = t;
  }
}

__global__ void fill_kernel(const int* __restrict__ src, const int* __restrict__ dst,
                            int* __restrict__ cur, int* __restrict__ eidx, int E) {
  int base = (blockIdx.x * blockDim.x + threadIdx.x) * 4;
  if (base + 3 < E) {
    int4 d = *(const int4*)&dst[base];
    int4 s = *(const int4*)&src[base];
    int p0 = atomicAdd(&cur[d.x], 1);
    int p1 = atomicAdd(&cur[d.y], 1);
    int p2 = atomicAdd(&cur[d.z], 1);
    int p3 = atomicAdd(&cur[d.w], 1);
    eidx[p0] = s.x; eidx[p1] = s.y; eidx[p2] = s.z; eidx[p3] = s.w;
  } else {
    for (int e = base; e < E; ++e) {
      int p = atomicAdd(&cur[dst[e]], 1);
      eidx[p] = src[e];
    }
  }
}

// ===========================================================================
// Fallback prep: blocks [0,128) transpose weights; rest pack P0 = [nf|H] f16
// ===========================================================================
__global__ __launch_bounds__(256) void prep_kernel(
    const float* __restrict__ Wm, const float* __restrict__ Wz,
    const float* __restrict__ Wr, const float* __restrict__ Wh,
    f16* __restrict__ WtM, f16* __restrict__ WtZR, f16* __restrict__ WtH,
    const float* __restrict__ nf, const float* __restrict__ H,
    f16* __restrict__ P0, int N) {
  const int bid = blockIdx.x;
  if (bid < 128) {
    __shared__ float tile[32][33];
    const int t = bid;
    const int x = t & 7, y = (t >> 3) & 3, z = t >> 5;
    const float* W;
    f16* O;
    int K;
    switch (z) {
      case 0: W = Wm; O = WtM; K = 128; break;
      case 1: W = Wz; O = WtZR; K = 256; break;
      case 2: W = Wr; O = WtZR + 128 * 256; K = 256; break;
      default: W = Wh; O = WtH; K = 256; break;
    }
    int bk = x * 32, bn = y * 32;
    if (bk >= K) return;
    int tx = threadIdx.x & 31, ty = threadIdx.x >> 5;
    #pragma unroll
    for (int i = 0; i < 4; ++i)
      tile[ty + 8 * i][tx] = W[(size_t)(bk + ty + 8 * i) * 128 + bn + tx];
    __syncthreads();
    #pragma unroll
    for (int i = 0; i < 4; ++i)
      O[(size_t)(bn + ty + 8 * i) * K + bk + tx] = (f16)tile[tx][ty + 8 * i];
  } else {
    const int w = (bid - 128) * 4 + (threadIdx.x >> 6);
    if (w >= N) return;
    int lane = threadIdx.x & 63;
    const float* S = (lane < 32) ? nf : H;
    int c = (lane & 31) * 4;
    float4 u = *(const float4*)&S[(size_t)w * 128 + c];
    f16x4 o = {(f16)u.x, (f16)u.y, (f16)u.z, (f16)u.w};
    *(f16x4*)&P0[(size_t)w * 256 + (lane < 32 ? 0 : 128) + c] = o;
  }
}

// ===========================================================================
// Gather v4: each 16/32-lane GROUP owns one node (4 or 2 nodes/wave).
// ===========================================================================
template <int COLS, typename IDX>
__global__ __launch_bounds__(256) void gather(const f16* __restrict__ P,
                                              const int* __restrict__ off,
                                              const IDX* __restrict__ eidx,
                                              f16* __restrict__ O, int N) {
  constexpr int NG = (COLS == 256) ? 2 : 4;
  constexpr int GL = 64 / NG;
  constexpr int SH = (COLS == 256) ? 9 : 8;
  int gid = blockIdx.x * blockDim.x + threadIdx.x;
  int wave = gid >> 6;
  int lane = threadIdx.x & 63;
  int g = lane / GL, lg = lane % GL;
  int node = wave * NG + g;
  if (node >= N) return;
  const int beg = off[node], end = off[node + 1];
  const char* base = (const char*)P + lg * 16;
  float a0 = 0.f, a1 = 0.f, a2 = 0.f, a3 = 0.f;
  float a4 = 0.f, a5 = 0.f, a6 = 0.f, a7 = 0.f;
  int j = beg;
  for (; j + 8 <= end; j += 8) {
    f16x8 v[8];
    #pragma unroll
    for (int u = 0; u < 8; ++u)
      v[u] = *(const f16x8*)(base + (((int)eidx[j + u]) << SH));
    #pragma unroll
    for (int u = 0; u < 8; ++u) {
      a0 += (float)v[u][0]; a1 += (float)v[u][1];
      a2 += (float)v[u][2]; a3 += (float)v[u][3];
      a4 += (float)v[u][4]; a5 += (float)v[u][5];
      a6 += (float)v[u][6]; a7 += (float)v[u][7];
    }
  }
  for (; j < end; ++j) {
    f16x8 v = *(const f16x8*)(base + (((int)eidx[j]) << SH));
    a0 += (float)v[0]; a1 += (float)v[1]; a2 += (float)v[2]; a3 += (float)v[3];
    a4 += (float)v[4]; a5 += (float)v[5]; a6 += (float)v[6]; a7 += (float)v[7];
  }
  f16x8 o = {(f16)a0, (f16)a1, (f16)a2, (f16)a3, (f16)a4, (f16)a5, (f16)a6, (f16)a7};
  *(f16x8*)&O[(size_t)node * COLS + lg * 8] = o;
}

// ===========================================================================
// MFMA GEMM v3: 64x128 tile, 4 waves, BK=64, double-buffered LDS, counted
// vmcnt, raw s_barrier, XOR-granule swizzle, global_load_lds staging.
// Hh = f16 H with row stride 256 (P0's hi half) — replaces f32 H reads.
// EPI 0: O0 = relu(acc+b0)
// EPI 1: coff==0: O0 = sig(acc+b0);  coff!=0: O1 = sig(acc+b1)*Hh
// EPI 2: Ofp = Zh*Hh + (1-Zh)*tanh(acc+b0)
// ===========================================================================
template <int TERMS, int EPI>
__global__ __launch_bounds__(256) void gemm_mfma(
    const f16* __restrict__ A0, int lda0, const f16* __restrict__ A1, int lda1,
    const f16* __restrict__ Wt,
    const float* __restrict__ b0, const float* __restrict__ b1,
    const f16* __restrict__ Hh, const f16* __restrict__ Zh,
    f16* __restrict__ O0, f16* __restrict__ O1, float* __restrict__ Ofp, int N) {
  constexpr int KTOT = TERMS * 128;
  constexpr int T = KTOT / 64;
  __shared__ __align__(16) f16 As[2][64][64];
  __shared__ __align__(16) f16 Bs[2][128][64];
  const int tid = threadIdx.x;
  const int l = tid & 63;
  const int wv = __builtin_amdgcn_readfirstlane(tid >> 6);
  const int fr = l & 15;
  const int q = l >> 4;
  const int brow = blockIdx.x * 64;
  const int coff = blockIdx.y * 128;
  const int rowA = wv * 16 + fr;
  const int sl8 = l >> 3, sg = l & 7;

  f32x4_t acc[8];
  #pragma unroll
  for (int n = 0; n < 8; ++n) acc[n] = (f32x4_t)0.0f;

  auto stage = [&](int t, int buf) {
    const bool sel1 = (TERMS == 2) && (t >= 2);
    const f16* __restrict__ A = sel1 ? A1 : A0;
    const int lda = sel1 ? lda1 : lda0;
    const int klocal = (t & 1) * 64;
    const int kk = t * 64;
    f16* Asf = &As[buf][0][0];
    f16* Bsf = &Bs[buf][0][0];
    #pragma unroll
    for (int c = 0; c < 2; ++c) {
      int chunk = wv + c * 4;
      int row = chunk * 8 + sl8;
      int gs = sg ^ (row & 7);
      int grow = brow + row;
      if (grow > N - 1) grow = N - 1;
      GLDS16(A + (size_t)grow * lda + klocal + gs * 8, Asf + chunk * 512);
    }
    #pragma unroll
    for (int c = 0; c < 4; ++c) {
      int chunk = wv + c * 4;
      int col = chunk * 8 + sl8;
      int gs = sg ^ (col & 7);
      GLDS16(Wt + (size_t)(coff + col) * KTOT + kk + gs * 8, Bsf + chunk * 512);
    }
  };

  stage(0, 0);
  #pragma unroll
  for (int t = 0; t < T; ++t) {
    if (t + 1 < T) {
      stage(t + 1, (t + 1) & 1);
      asm volatile("s_waitcnt vmcnt(6)" ::: "memory");
    } else {
      asm volatile("s_waitcnt vmcnt(0)" ::: "memory");
    }
    __builtin_amdgcn_s_barrier();
    const int buf = t & 1;
    #pragma unroll
    for (int ks = 0; ks < 2; ++ks) {
      f16x8 a = *(const f16x8*)&As[buf][rowA][((ks * 4 + q) ^ (rowA & 7)) * 8];
      f16x8 bfr[8];
      #pragma unroll
      for (int n = 0; n < 8; ++n) {
        int colB = n * 16 + fr;
        bfr[n] = *(const f16x8*)&Bs[buf][colB][((ks * 4 + q) ^ (colB & 7)) * 8];
      }
      #pragma unroll
      for (int n = 0; n < 8; ++n)
        acc[n] = __builtin_amdgcn_mfma_f32_16x16x32_f16(a, bfr[n], acc[n], 0, 0, 0);
    }
    asm volatile("s_waitcnt lgkmcnt(0)" ::: "memory");
    __builtin_amdgcn_s_barrier();
  }

  const int row0 = brow + wv * 16 + q * 4;
  #pragma unroll
  for (int n = 0; n < 8; ++n) {
    int colL = n * 16 + fr;
    if (EPI == 0) {
      float bias = b0[colL];
      #pragma unroll
      for (int r = 0; r < 4; ++r) {
        int row = row0 + r;
        if (row < N)
          O0[(size_t)row * 128 + colL] = (f16)fmaxf(acc[n][r] + bias, 0.f);
      }
    } else if (EPI == 1) {
      if (coff == 0) {
        float bias = b0[colL];
        #pragma unroll
        for (int r = 0; r < 4; ++r) {
          int row = row0 + r;
          if (row < N)
            O0[(size_t)row * 128 + colL] = (f16)sigmoidf(acc[n][r] + bias);
        }
      } else {
        float bias = b1[colL];
        #pragma unroll
        for (int r = 0; r < 4; ++r) {
          int row = row0 + r;
          if (row < N) {
            float hv = (float)Hh[(size_t)row * 256 + colL];
            float g = sigmoidf(acc[n][r] + bias) * hv;
            O1[(size_t)row * 128 + colL] = (f16)g;
          }
        }
      }
    } else {
      float bias = b0[colL];
      #pragma unroll
      for (int r = 0; r < 4; ++r) {
        int row = row0 + r;
        if (row < N) {
          float ht = tanhf(acc[n][r] + bias);
          float z = (float)Zh[(size_t)row * 128 + colL];
          float hv = (float)Hh[(size_t)row * 256 + colL];
          Ofp[(size_t)row * 128 + colL] = z * hv + (1.0f - z) * ht;
        }
      }
    }
  }
}

// ===========================================================================

extern "C" void kernel_launch(void* const* d_in, const int* in_sizes, int n_in,
                              void* d_out, int out_size, void* d_ws, size_t ws_size,
                              hipStream_t stream) {
  const float* nf = (const float*)d_in[0];
  const float* H  = (const float*)d_in[1];
  const int*   ei = (const int*)d_in[2];
  const float* Wm = (const float*)d_in[3];
  const float* bm = (const float*)d_in[4];
  const float* Wz = (const float*)d_in[5];
  const float* bz = (const float*)d_in[6];
  const float* Wr = (const float*)d_in[7];
  const float* br = (const float*)d_in[8];
  const float* Wh = (const float*)d_in[9];
  const float* bh = (const float*)d_in[10];
  float* out = (float*)d_out;

  const int N = in_sizes[0] / 128;
  const int E = in_sizes[2] / 2;
  const int* src = ei;
  const int* dst = ei + E;

  char* ws = (char*)d_ws;
  size_t o = 0;
  auto alloc = [&](size_t bytes) {
    char* p = ws + o;
    o = (o + bytes + 511) & ~(size_t)511;
    return p;
  };
  const int NB = (N + 255) >> 8;
  const int nhb = (E + 4095) / 4096;
  const int nbch = (N + 1023) / 1024;
  int* hrows  = (int*)alloc((size_t)nhb * 256 * 4);
  int* gcurP  = (int*)alloc((size_t)NB * 16 * 4);
  int* bbases = (int*)alloc((size_t)(NB + 1) * 4);
  unsigned int* bin = (unsigned int*)alloc((size_t)E * 4);
  int* off    = (int*)alloc((size_t)(N + 1) * 4);
  int* cur    = (int*)alloc((size_t)(N + 1) * 4);   // big-N fallback
  int* cnt    = (int*)alloc((size_t)N * 4);          // big-N fallback
  int* psum   = (int*)alloc((size_t)nbch * 4);       // big-N fallback
  void* eidx  = (void*)alloc((size_t)E * 4);
  f16* WtM    = (f16*)alloc((size_t)128 * 128 * 2);
  f16* WtZR   = (f16*)alloc((size_t)256 * 256 * 2);
  f16* WtH    = (f16*)alloc((size_t)128 * 256 * 2);
  f16* P0     = (f16*)alloc((size_t)N * 256 * 2);   // [nf|H] f16, ALIVE to end
  f16* X      = (f16*)alloc((size_t)N * 128 * 2);
  f16* AX     = (f16*)alloc((size_t)N * 128 * 2);
  f16* G      = (f16*)alloc((size_t)N * 128 * 2);
  f16* AG     = (f16*)alloc((size_t)N * 128 * 2);
  f16* AP0    = (f16*)d_out;                        // dead before final write
  f16* Zh     = X;                                  // X dead after gather(X)
  const f16* Hh = P0 + 128;                         // f16 H, row stride 256

  const bool small = (N <= 65536);

  // --- CSR build + prep ---
  bool coop_done = false;
  if (small) {
    const int NBLK = (nhb > NB) ? nhb : NB;
    const int* src_a = src; const int* dst_a = dst;
    int E_a = E, N_a = N, NB_a = NB, nhb_a = nhb;
    unsigned short* eidx_a = (unsigned short*)eidx;
    const float* Wm_a = Wm; const float* Wz_a = Wz;
    const float* Wr_a = Wr; const float* Wh_a = Wh;
    const float* nf_a = nf; const float* H_a = H;
    f16* WtM_a = WtM; f16* WtZR_a = WtZR; f16* WtH_a = WtH; f16* P0_a = P0;
    int* hrows_a = hrows; int* bbases_a = bbases; int* gcurP_a = gcurP;
    unsigned int* bin_a = bin; int* off_a = off;
    void* kargs[] = {
      (void*)&src_a, (void*)&dst_a, (void*)&E_a, (void*)&N_a,
      (void*)&NB_a, (void*)&nhb_a, (void*)&hrows_a, (void*)&bbases_a,
      (void*)&gcurP_a, (void*)&bin_a, (void*)&eidx_a, (void*)&off_a,
      (void*)&Wm_a, (void*)&Wz_a, (void*)&Wr_a, (void*)&Wh_a,
      (void*)&WtM_a, (void*)&WtZR_a, (void*)&WtH_a,
      (void*)&nf_a, (void*)&H_a, (void*)&P0_a
    };
    hipError_t ce = hipLaunchCooperativeKernel((const void*)csr_prep_coop,
                                               dim3(NBLK), dim3(256), kargs, 0, stream);
    if (ce == hipSuccess) {
      coop_done = true;
    } else {
      (void)hipGetLastError();   // clear and fall back
    }
  }
  if (!coop_done) {
    if (small) {
      bucket_hist2<<<nhb, 256, 0, stream>>>(dst, hrows, E);
      bucket_scan2<<<1, 256, 0, stream>>>(hrows, nhb, bbases, gcurP, NB);
      partition_v2<<<nhb, 256, 0, stream>>>(src, dst, gcurP, bin, E, NB);
      bucket_sort<<<NB, 256, 0, stream>>>(bin, bbases, (unsigned short*)eidx, off, N, NB);
    } else {
      const int qblk = ((E + 3) / 4 + 255) / 256;
      zero_ints<<<(N + 255) / 256, 256, 0, stream>>>(cnt, N);
      count_kernel<<<qblk, 256, 0, stream>>>(dst, cnt, E);
      scan_local<<<nbch, 1024, 0, stream>>>(cnt, off, psum, N);
      scan_carry<<<1, 1024, 0, stream>>>(psum, off, cur, nbch, N);
      scan_add<<<nbch, 1024, 0, stream>>>(off, cur, psum, N);
      fill_kernel<<<qblk, 256, 0, stream>>>(src, dst, cur, (int*)eidx, E);
    }
    prep_kernel<<<128 + (N + 3) / 4, 256, 0, stream>>>(
        Wm, Wz, Wr, Wh, WtM, WtZR, WtH, nf, H, P0, N);
  }

  const int mblk = (N + 63) / 64;
  const int g256 = (N + 7) / 8;     // 2 nodes/wave, 4 waves/block
  const int g128 = (N + 15) / 16;   // 4 nodes/wave

  // --- AP0 = Agg([nf|H]) ---
  if (small)
    gather<256, unsigned short><<<g256, 256, 0, stream>>>(P0, off, (const unsigned short*)eidx, AP0, N);
  else
    gather<256, int><<<g256, 256, 0, stream>>>(P0, off, (const int*)eidx, AP0, N);

  // --- X = relu(Anf @ Wm + bm) ---
  gemm_mfma<1, 0><<<dim3(mblk, 1), 256, 0, stream>>>(
      AP0, 256, nullptr, 0, WtM, bm, nullptr, nullptr, nullptr, X, nullptr, nullptr, N);

  // --- AX = Agg(X) ---
  if (small)
    gather<128, unsigned short><<<g128, 256, 0, stream>>>(X, off, (const unsigned short*)eidx, AX, N);
  else
    gather<128, int><<<g128, 256, 0, stream>>>(X, off, (const int*)eidx, AX, N);

  // --- Z = sig([AX,AH]@Wz+bz), G = sig([AX,AH]@Wr+br)*Hh ---
  gemm_mfma<2, 1><<<dim3(mblk, 2), 256, 0, stream>>>(
      AX, 128, AP0 + 128, 256, WtZR, bz, br, Hh, nullptr, Zh, G, nullptr, N);

  // --- AG = Agg(G) ---
  if (small)
    gather<128, unsigned short><<<g128, 256, 0, stream>>>(G, off, (const unsigned short*)eidx, AG, N);
  else
    gather<128, int><<<g128, 256, 0, stream>>>(G, off, (const int*)eidx, AG, N);

  // --- out = Zh*Hh + (1-Zh)*tanh([AX,AG]@Wh + bh) ---
  gemm_mfma<2, 2><<<dim3(mblk, 1), 256, 0, stream>>>(
      AX, 128, AG, 128, WtH, bh, nullptr, Hh, Zh, nullptr, nullptr, out, N);
}

// Round 12
// 282.094 us; speedup vs baseline: 1.3012x; 1.3012x over previous
//
#include <hip/hip_runtime.h>
#include <hip/hip_fp16.h>
#include <math.h>

typedef _Float16 f16;
typedef f16 f16x2 __attribute__((ext_vector_type(2)));
typedef f16 f16x4 __attribute__((ext_vector_type(4)));
typedef f16 f16x8 __attribute__((ext_vector_type(8)));
typedef float f32x4_t __attribute__((ext_vector_type(4)));

__device__ __forceinline__ float sigmoidf(float x) {
  return 1.0f / (1.0f + __expf(-x));
}

// direct-to-LDS 16B copy: LDS dest = wave-uniform base + lane*16
#define GLDS16(gp, lp)                                                     \
  __builtin_amdgcn_global_load_lds(                                        \
      (const __attribute__((address_space(1))) void*)(gp),                 \
      (__attribute__((address_space(3))) void*)(lp), 16, 0, 0)

__global__ void zero_ints(int* __restrict__ p, int n) {
  int i = blockIdx.x * blockDim.x + threadIdx.x;
  if (i < n) p[i] = 0;
}

// ===========================================================================
// CSR build v4 (N <= 65536): 256-node radix buckets, separate dispatches
// (lesson r8/r11: latency-bound phases need cross-block dispatch overlap,
// never barrier-fused).  hist -> scan -> partition (block-local staging,
// one global reserve per block-bucket) -> per-bucket counting sort.
// ===========================================================================
__global__ __launch_bounds__(256) void bucket_hist2(const int* __restrict__ dst,
                                                    int* __restrict__ hrows, int E) {
  __shared__ int h[256];
  h[threadIdx.x] = 0;
  __syncthreads();
  int base = blockIdx.x * 4096;
  int lim = min(base + 4096, E);
  for (int e = base + threadIdx.x; e < lim; e += 256)
    atomicAdd(&h[dst[e] >> 8], 1);
  __syncthreads();
  hrows[blockIdx.x * 256 + threadIdx.x] = h[threadIdx.x];
}

__global__ __launch_bounds__(256) void bucket_scan2(const int* __restrict__ hrows,
                                                    int nhb, int* __restrict__ bbases,
                                                    int* __restrict__ gcurP, int NB) {
  __shared__ int wsum[4];
  const int tid = threadIdx.x, lane = tid & 63, wid = tid >> 6;
  int v = 0;
  for (int b = 0; b < nhb; ++b) v += hrows[b * 256 + tid];
  if (tid >= NB) v = 0;
  int x = v;
  #pragma unroll
  for (int d = 1; d < 64; d <<= 1) { int y = __shfl_up(x, d); if (lane >= d) x += y; }
  if (lane == 63) wsum[wid] = x;
  __syncthreads();
  if (wid == 0 && lane < 4) {
    int ws = wsum[lane];
    #pragma unroll
    for (int d = 1; d < 4; d <<= 1) { int y = __shfl_up(ws, d); if (lane >= d) ws += y; }
    wsum[lane] = ws;
  }
  __syncthreads();
  int excl = x - v + (wid ? wsum[wid - 1] : 0);
  if (tid < NB) { bbases[tid] = excl; gcurP[tid * 16] = excl; }
  if (tid == NB - 1) bbases[NB] = excl + v;
}

__global__ __launch_bounds__(256) void partition_v2(const int* __restrict__ src,
                                                    const int* __restrict__ dst,
                                                    int* __restrict__ gcurP,
                                                    unsigned int* __restrict__ bin,
                                                    int E, int NB) {
  __shared__ int bhist[256];
  __shared__ int bofs[257];
  __shared__ int gbase[256];
  __shared__ unsigned int recs[4096];
  const int tid = threadIdx.x;
  const int base = blockIdx.x * 4096;
  bhist[tid] = 0;
  __syncthreads();
  unsigned int rec[16];
  int bk[16];
  #pragma unroll
  for (int k = 0; k < 16; ++k) {
    int e = base + tid + k * 256;
    if (e < E) {
      int d = dst[e];
      rec[k] = (unsigned int)(src[e] & 0xFFFF) | ((unsigned int)(d & 255) << 16);
      bk[k] = d >> 8;
      atomicAdd(&bhist[bk[k]], 1);
    } else {
      bk[k] = -1;
    }
  }
  __syncthreads();
  if (tid < 64) {
    int l = tid;
    int v0 = bhist[4 * l], v1 = bhist[4 * l + 1];
    int v2 = bhist[4 * l + 2], v3 = bhist[4 * l + 3];
    int s1 = v0 + v1, s2 = s1 + v2, t = s2 + v3;
    int x = t;
    #pragma unroll
    for (int d = 1; d < 64; d <<= 1) { int y = __shfl_up(x, d); if (l >= d) x += y; }
    int basex = x - t;
    bofs[4 * l] = basex;
    bofs[4 * l + 1] = basex + v0;
    bofs[4 * l + 2] = basex + s1;
    bofs[4 * l + 3] = basex + s2;
    if (l == 63) bofs[256] = x;
  }
  __syncthreads();
  if (tid < NB && bhist[tid] > 0)
    gbase[tid] = atomicAdd(&gcurP[tid * 16], bhist[tid]);
  __syncthreads();
  bhist[tid] = bofs[tid];
  __syncthreads();
  #pragma unroll
  for (int k = 0; k < 16; ++k) {
    if (bk[k] >= 0) {
      int p = atomicAdd(&bhist[bk[k]], 1);
      recs[p] = rec[k];
    }
  }
  __syncthreads();
  const int total = bofs[256];
  for (int i = tid; i < total; i += 256) {
    int lo = 0, hi = 256;
    #pragma unroll
    for (int s = 0; s < 8; ++s) {
      int mid = (lo + hi) >> 1;
      if (bofs[mid] <= i) lo = mid; else hi = mid;
    }
    bin[gbase[lo] + (i - bofs[lo])] = recs[i];
  }
}

__global__ __launch_bounds__(256) void bucket_sort(const unsigned int* __restrict__ bin,
                                                   const int* __restrict__ bbases,
                                                   unsigned short* __restrict__ eidx,
                                                   int* __restrict__ off,
                                                   int N, int NB) {
  const int b = blockIdx.x;
  const int bb = bbases[b], be = bbases[b + 1];
  const int cntb = be - bb;
  const int d0 = b << 8;
  const int ndst = min(256, N - d0);
  __shared__ int hist[256];
  __shared__ int lofs[256];
  __shared__ int cnt2[256];
  __shared__ unsigned short srt[8192];
  const int tid = threadIdx.x;
  hist[tid] = 0;
  cnt2[tid] = 0;
  __syncthreads();
  for (int i = bb + tid; i < be; i += 256)
    atomicAdd(&hist[(bin[i] >> 16) & 255], 1);
  __syncthreads();
  if (tid < 64) {
    int l = tid;
    int v0 = hist[4 * l], v1 = hist[4 * l + 1], v2 = hist[4 * l + 2], v3 = hist[4 * l + 3];
    int s1 = v0 + v1, s2 = s1 + v2, t = s2 + v3;
    int x = t;
    #pragma unroll
    for (int d = 1; d < 64; d <<= 1) { int y = __shfl_up(x, d); if (l >= d) x += y; }
    int basex = x - t;
    lofs[4 * l] = basex;
    lofs[4 * l + 1] = basex + v0;
    lofs[4 * l + 2] = basex + s1;
    lofs[4 * l + 3] = basex + s2;
  }
  __syncthreads();
  if (tid < ndst) off[d0 + tid] = bb + lofs[tid];
  if (b == NB - 1 && tid == 0) off[N] = be;
  if (cntb <= 8192) {
    for (int i = bb + tid; i < be; i += 256) {
      unsigned int r = bin[i];
      int ld = (r >> 16) & 255;
      int p = lofs[ld] + atomicAdd(&cnt2[ld], 1);
      srt[p] = (unsigned short)(r & 0xFFFF);
    }
    __syncthreads();
    for (int i = tid; i < cntb; i += 256) eidx[bb + i] = srt[i];
  } else {
    for (int i = bb + tid; i < be; i += 256) {
      unsigned int r = bin[i];
      int ld = (r >> 16) & 255;
      int p = bb + lofs[ld] + atomicAdd(&cnt2[ld], 1);
      eidx[p] = (unsigned short)(r & 0xFFFF);
    }
  }
}

// ===========================================================================
// Fallback CSR build (N > 65536)
// ===========================================================================
__global__ void count_kernel(const int* __restrict__ dst, int* __restrict__ cnt, int E) {
  int base = (blockIdx.x * blockDim.x + threadIdx.x) * 4;
  if (base + 3 < E) {
    int4 d = *(const int4*)&dst[base];
    atomicAdd(&cnt[d.x], 1);
    atomicAdd(&cnt[d.y], 1);
    atomicAdd(&cnt[d.z], 1);
    atomicAdd(&cnt[d.w], 1);
  } else {
    for (int e = base; e < E; ++e) atomicAdd(&cnt[dst[e]], 1);
  }
}

__global__ __launch_bounds__(1024) void scan_local(const int* __restrict__ cnt,
                                                   int* __restrict__ off,
                                                   int* __restrict__ psum, int n) {
  __shared__ int wsum[16];
  const int tid = threadIdx.x, lane = tid & 63, wid = tid >> 6;
  int i = blockIdx.x * 1024 + tid;
  int v = (i < n) ? cnt[i] : 0;
  int x = v;
  #pragma unroll
  for (int d = 1; d < 64; d <<= 1) { int y = __shfl_up(x, d); if (lane >= d) x += y; }
  if (lane == 63) wsum[wid] = x;
  __syncthreads();
  if (wid == 0) {
    int ws = (lane < 16) ? wsum[lane] : 0;
    #pragma unroll
    for (int d = 1; d < 16; d <<= 1) { int y = __shfl_up(ws, d); if (lane >= d) ws += y; }
    if (lane < 16) wsum[lane] = ws;
  }
  __syncthreads();
  int excl = x - v + (wid ? wsum[wid - 1] : 0);
  if (i < n) off[i] = excl;
  if (tid == 1023) psum[blockIdx.x] = wsum[15];
}

__global__ __launch_bounds__(1024) void scan_carry(int* __restrict__ psum,
                                                   int* __restrict__ off,
                                                   int* __restrict__ cur, int nb, int n) {
  __shared__ int wsum[16];
  const int tid = threadIdx.x, lane = tid & 63, wid = tid >> 6;
  int v = (tid < nb) ? psum[tid] : 0;
  int x = v;
  #pragma unroll
  for (int d = 1; d < 64; d <<= 1) { int y = __shfl_up(x, d); if (lane >= d) x += y; }
  if (lane == 63) wsum[wid] = x;
  __syncthreads();
  if (wid == 0) {
    int ws = (lane < 16) ? wsum[lane] : 0;
    #pragma unroll
    for (int d = 1; d < 16; d <<= 1) { int y = __shfl_up(ws, d); if (lane >= d) ws += y; }
    if (lane < 16) wsum[lane] = ws;
  }
  __syncthreads();
  int excl = x - v + (wid ? wsum[wid - 1] : 0);
  if (tid < nb) psum[tid] = excl;
  if (tid == 1023) { off[n] = wsum[15]; cur[n] = wsum[15]; }
}

__global__ __launch_bounds__(1024) void scan_add(int* __restrict__ off, int* __restrict__ cur,
                                                 const int* __restrict__ psum, int n) {
  int i = blockIdx.x * 1024 + threadIdx.x;
  if (i < n) {
    int t = off[i] + psum[blockIdx.x];
    off[i] = t;
    cur[i] = t;
  }
}

__global__ void fill_kernel(const int* __restrict__ src, const int* __restrict__ dst,
                            int* __restrict__ cur, int* __restrict__ eidx, int E) {
  int base = (blockIdx.x * blockDim.x + threadIdx.x) * 4;
  if (base + 3 < E) {
    int4 d = *(const int4*)&dst[base];
    int4 s = *(const int4*)&src[base];
    int p0 = atomicAdd(&cur[d.x], 1);
    int p1 = atomicAdd(&cur[d.y], 1);
    int p2 = atomicAdd(&cur[d.z], 1);
    int p3 = atomicAdd(&cur[d.w], 1);
    eidx[p0] = s.x; eidx[p1] = s.y; eidx[p2] = s.z; eidx[p3] = s.w;
  } else {
    for (int e = base; e < E; ++e) {
      int p = atomicAdd(&cur[dst[e]], 1);
      eidx[p] = src[e];
    }
  }
}

// ===========================================================================
// Prep: blocks [0,128) transpose weights; rest pack P0 = [nf|H] f16 [N,256]
// ===========================================================================
__global__ __launch_bounds__(256) void prep_kernel(
    const float* __restrict__ Wm, const float* __restrict__ Wz,
    const float* __restrict__ Wr, const float* __restrict__ Wh,
    f16* __restrict__ WtM, f16* __restrict__ WtZR, f16* __restrict__ WtH,
    const float* __restrict__ nf, const float* __restrict__ H,
    f16* __restrict__ P0, int N) {
  const int bid = blockIdx.x;
  if (bid < 128) {
    __shared__ float tile[32][33];
    const int t = bid;
    const int x = t & 7, y = (t >> 3) & 3, z = t >> 5;
    const float* W;
    f16* O;
    int K;
    switch (z) {
      case 0: W = Wm; O = WtM; K = 128; break;
      case 1: W = Wz; O = WtZR; K = 256; break;
      case 2: W = Wr; O = WtZR + 128 * 256; K = 256; break;
      default: W = Wh; O = WtH; K = 256; break;
    }
    int bk = x * 32, bn = y * 32;
    if (bk >= K) return;
    int tx = threadIdx.x & 31, ty = threadIdx.x >> 5;
    #pragma unroll
    for (int i = 0; i < 4; ++i)
      tile[ty + 8 * i][tx] = W[(size_t)(bk + ty + 8 * i) * 128 + bn + tx];
    __syncthreads();
    #pragma unroll
    for (int i = 0; i < 4; ++i)
      O[(size_t)(bn + ty + 8 * i) * K + bk + tx] = (f16)tile[tx][ty + 8 * i];
  } else {
    const int w = (bid - 128) * 4 + (threadIdx.x >> 6);
    if (w >= N) return;
    int lane = threadIdx.x & 63;
    const float* S = (lane < 32) ? nf : H;
    int c = (lane & 31) * 4;
    float4 u = *(const float4*)&S[(size_t)w * 128 + c];
    f16x4 o = {(f16)u.x, (f16)u.y, (f16)u.z, (f16)u.w};
    *(f16x4*)&P0[(size_t)w * 256 + (lane < 32 ? 0 : 128) + c] = o;
  }
}

// ===========================================================================
// Gather v4: each 16/32-lane GROUP owns one node (4 or 2 nodes/wave).
// f16x8 (16B) per lane covers the whole row; 8-deep unroll.
// (Structural floor: 3.5 TB/s L2-fill, invariant across 4 structure probes.)
// ===========================================================================
template <int COLS, typename IDX>
__global__ __launch_bounds__(256) void gather(const f16* __restrict__ P,
                                              const int* __restrict__ off,
                                              const IDX* __restrict__ eidx,
                                              f16* __restrict__ O, int N) {
  constexpr int NG = (COLS == 256) ? 2 : 4;
  constexpr int GL = 64 / NG;
  constexpr int SH = (COLS == 256) ? 9 : 8;
  int gid = blockIdx.x * blockDim.x + threadIdx.x;
  int wave = gid >> 6;
  int lane = threadIdx.x & 63;
  int g = lane / GL, lg = lane % GL;
  int node = wave * NG + g;
  if (node >= N) return;
  const int beg = off[node], end = off[node + 1];
  const char* base = (const char*)P + lg * 16;
  float a0 = 0.f, a1 = 0.f, a2 = 0.f, a3 = 0.f;
  float a4 = 0.f, a5 = 0.f, a6 = 0.f, a7 = 0.f;
  int j = beg;
  for (; j + 8 <= end; j += 8) {
    f16x8 v[8];
    #pragma unroll
    for (int u = 0; u < 8; ++u)
      v[u] = *(const f16x8*)(base + (((int)eidx[j + u]) << SH));
    #pragma unroll
    for (int u = 0; u < 8; ++u) {
      a0 += (float)v[u][0]; a1 += (float)v[u][1];
      a2 += (float)v[u][2]; a3 += (float)v[u][3];
      a4 += (float)v[u][4]; a5 += (float)v[u][5];
      a6 += (float)v[u][6]; a7 += (float)v[u][7];
    }
  }
  for (; j < end; ++j) {
    f16x8 v = *(const f16x8*)(base + (((int)eidx[j]) << SH));
    a0 += (float)v[0]; a1 += (float)v[1]; a2 += (float)v[2]; a3 += (float)v[3];
    a4 += (float)v[4]; a5 += (float)v[5]; a6 += (float)v[6]; a7 += (float)v[7];
  }
  f16x8 o = {(f16)a0, (f16)a1, (f16)a2, (f16)a3, (f16)a4, (f16)a5, (f16)a6, (f16)a7};
  *(f16x8*)&O[(size_t)node * COLS + lg * 8] = o;
}

// ===========================================================================
// MFMA GEMM v3: 64x128 tile, 4 waves, BK=64, double-buffered LDS, counted
// vmcnt, raw s_barrier, XOR-granule swizzle, global_load_lds staging.
// Hh = f16 H with row stride 256 (P0's hi half) — no f32 H traffic.
// EPI 0: O0 = relu(acc+b0)
// EPI 1: coff==0: O0 = sig(acc+b0);  coff!=0: O1 = sig(acc+b1)*Hh
// EPI 2: Ofp = Zh*Hh + (1-Zh)*tanh(acc+b0)
// ===========================================================================
template <int TERMS, int EPI>
__global__ __launch_bounds__(256) void gemm_mfma(
    const f16* __restrict__ A0, int lda0, const f16* __restrict__ A1, int lda1,
    const f16* __restrict__ Wt,
    const float* __restrict__ b0, const float* __restrict__ b1,
    const f16* __restrict__ Hh, const f16* __restrict__ Zh,
    f16* __restrict__ O0, f16* __restrict__ O1, float* __restrict__ Ofp, int N) {
  constexpr int KTOT = TERMS * 128;
  constexpr int T = KTOT / 64;
  __shared__ __align__(16) f16 As[2][64][64];
  __shared__ __align__(16) f16 Bs[2][128][64];
  const int tid = threadIdx.x;
  const int l = tid & 63;
  const int wv = __builtin_amdgcn_readfirstlane(tid >> 6);
  const int fr = l & 15;
  const int q = l >> 4;
  const int brow = blockIdx.x * 64;
  const int coff = blockIdx.y * 128;
  const int rowA = wv * 16 + fr;
  const int sl8 = l >> 3, sg = l & 7;

  f32x4_t acc[8];
  #pragma unroll
  for (int n = 0; n < 8; ++n) acc[n] = (f32x4_t)0.0f;

  auto stage = [&](int t, int buf) {
    const bool sel1 = (TERMS == 2) && (t >= 2);
    const f16* __restrict__ A = sel1 ? A1 : A0;
    const int lda = sel1 ? lda1 : lda0;
    const int klocal = (t & 1) * 64;
    const int kk = t * 64;
    f16* Asf = &As[buf][0][0];
    f16* Bsf = &Bs[buf][0][0];
    #pragma unroll
    for (int c = 0; c < 2; ++c) {
      int chunk = wv + c * 4;
      int row = chunk * 8 + sl8;
      int gs = sg ^ (row & 7);
      int grow = brow + row;
      if (grow > N - 1) grow = N - 1;
      GLDS16(A + (size_t)grow * lda + klocal + gs * 8, Asf + chunk * 512);
    }
    #pragma unroll
    for (int c = 0; c < 4; ++c) {
      int chunk = wv + c * 4;
      int col = chunk * 8 + sl8;
      int gs = sg ^ (col & 7);
      GLDS16(Wt + (size_t)(coff + col) * KTOT + kk + gs * 8, Bsf + chunk * 512);
    }
  };

  stage(0, 0);
  #pragma unroll
  for (int t = 0; t < T; ++t) {
    if (t + 1 < T) {
      stage(t + 1, (t + 1) & 1);
      asm volatile("s_waitcnt vmcnt(6)" ::: "memory");
    } else {
      asm volatile("s_waitcnt vmcnt(0)" ::: "memory");
    }
    __builtin_amdgcn_s_barrier();
    const int buf = t & 1;
    #pragma unroll
    for (int ks = 0; ks < 2; ++ks) {
      f16x8 a = *(const f16x8*)&As[buf][rowA][((ks * 4 + q) ^ (rowA & 7)) * 8];
      f16x8 bfr[8];
      #pragma unroll
      for (int n = 0; n < 8; ++n) {
        int colB = n * 16 + fr;
        bfr[n] = *(const f16x8*)&Bs[buf][colB][((ks * 4 + q) ^ (colB & 7)) * 8];
      }
      #pragma unroll
      for (int n = 0; n < 8; ++n)
        acc[n] = __builtin_amdgcn_mfma_f32_16x16x32_f16(a, bfr[n], acc[n], 0, 0, 0);
    }
    asm volatile("s_waitcnt lgkmcnt(0)" ::: "memory");
    __builtin_amdgcn_s_barrier();
  }

  const int row0 = brow + wv * 16 + q * 4;
  #pragma unroll
  for (int n = 0; n < 8; ++n) {
    int colL = n * 16 + fr;
    if (EPI == 0) {
      float bias = b0[colL];
      #pragma unroll
      for (int r = 0; r < 4; ++r) {
        int row = row0 + r;
        if (row < N)
          O0[(size_t)row * 128 + colL] = (f16)fmaxf(acc[n][r] + bias, 0.f);
      }
    } else if (EPI == 1) {
      if (coff == 0) {
        float bias = b0[colL];
        #pragma unroll
        for (int r = 0; r < 4; ++r) {
          int row = row0 + r;
          if (row < N)
            O0[(size_t)row * 128 + colL] = (f16)sigmoidf(acc[n][r] + bias);
        }
      } else {
        float bias = b1[colL];
        #pragma unroll
        for (int r = 0; r < 4; ++r) {
          int row = row0 + r;
          if (row < N) {
            float hv = (float)Hh[(size_t)row * 256 + colL];
            float g = sigmoidf(acc[n][r] + bias) * hv;
            O1[(size_t)row * 128 + colL] = (f16)g;
          }
        }
      }
    } else {
      float bias = b0[colL];
      #pragma unroll
      for (int r = 0; r < 4; ++r) {
        int row = row0 + r;
        if (row < N) {
          float ht = tanhf(acc[n][r] + bias);
          float z = (float)Zh[(size_t)row * 128 + colL];
          float hv = (float)Hh[(size_t)row * 256 + colL];
          Ofp[(size_t)row * 128 + colL] = z * hv + (1.0f - z) * ht;
        }
      }
    }
  }
}

// ===========================================================================

extern "C" void kernel_launch(void* const* d_in, const int* in_sizes, int n_in,
                              void* d_out, int out_size, void* d_ws, size_t ws_size,
                              hipStream_t stream) {
  const float* nf = (const float*)d_in[0];
  const float* H  = (const float*)d_in[1];
  const int*   ei = (const int*)d_in[2];
  const float* Wm = (const float*)d_in[3];
  const float* bm = (const float*)d_in[4];
  const float* Wz = (const float*)d_in[5];
  const float* bz = (const float*)d_in[6];
  const float* Wr = (const float*)d_in[7];
  const float* br = (const float*)d_in[8];
  const float* Wh = (const float*)d_in[9];
  const float* bh = (const float*)d_in[10];
  float* out = (float*)d_out;

  const int N = in_sizes[0] / 128;
  const int E = in_sizes[2] / 2;
  const int* src = ei;
  const int* dst = ei + E;

  char* ws = (char*)d_ws;
  size_t o = 0;
  auto alloc = [&](size_t bytes) {
    char* p = ws + o;
    o = (o + bytes + 511) & ~(size_t)511;
    return p;
  };
  const int NB = (N + 255) >> 8;
  const int nhb = (E + 4095) / 4096;
  const int nbch = (N + 1023) / 1024;
  int* hrows  = (int*)alloc((size_t)nhb * 256 * 4);
  int* gcurP  = (int*)alloc((size_t)NB * 16 * 4);
  int* bbases = (int*)alloc((size_t)(NB + 1) * 4);
  unsigned int* bin = (unsigned int*)alloc((size_t)E * 4);
  int* off    = (int*)alloc((size_t)(N + 1) * 4);
  int* cur    = (int*)alloc((size_t)(N + 1) * 4);   // big-N fallback
  int* cnt    = (int*)alloc((size_t)N * 4);          // big-N fallback
  int* psum   = (int*)alloc((size_t)nbch * 4);       // big-N fallback
  void* eidx  = (void*)alloc((size_t)E * 4);
  f16* WtM    = (f16*)alloc((size_t)128 * 128 * 2);
  f16* WtZR   = (f16*)alloc((size_t)256 * 256 * 2);
  f16* WtH    = (f16*)alloc((size_t)128 * 256 * 2);
  f16* P0     = (f16*)alloc((size_t)N * 256 * 2);   // [nf|H] f16, alive to end
  f16* X      = (f16*)alloc((size_t)N * 128 * 2);
  f16* AX     = (f16*)alloc((size_t)N * 128 * 2);
  f16* G      = (f16*)alloc((size_t)N * 128 * 2);
  f16* AG     = (f16*)alloc((size_t)N * 128 * 2);
  f16* AP0    = (f16*)d_out;                        // dead before final write
  f16* Zh     = X;                                  // X dead after gather(X)
  const f16* Hh = P0 + 128;                         // f16 H, row stride 256

  const bool small = (N <= 65536);

  // --- CSR build (separate dispatches; r11 lesson: never barrier-fuse) ---
  if (small) {
    bucket_hist2<<<nhb, 256, 0, stream>>>(dst, hrows, E);
    bucket_scan2<<<1, 256, 0, stream>>>(hrows, nhb, bbases, gcurP, NB);
    partition_v2<<<nhb, 256, 0, stream>>>(src, dst, gcurP, bin, E, NB);
    bucket_sort<<<NB, 256, 0, stream>>>(bin, bbases, (unsigned short*)eidx, off, N, NB);
  } else {
    const int qblk = ((E + 3) / 4 + 255) / 256;
    zero_ints<<<(N + 255) / 256, 256, 0, stream>>>(cnt, N);
    count_kernel<<<qblk, 256, 0, stream>>>(dst, cnt, E);
    scan_local<<<nbch, 1024, 0, stream>>>(cnt, off, psum, N);
    scan_carry<<<1, 1024, 0, stream>>>(psum, off, cur, nbch, N);
    scan_add<<<nbch, 1024, 0, stream>>>(off, cur, psum, N);
    fill_kernel<<<qblk, 256, 0, stream>>>(src, dst, cur, (int*)eidx, E);
  }

  // --- prep: weight transpose + input pack ---
  prep_kernel<<<128 + (N + 3) / 4, 256, 0, stream>>>(
      Wm, Wz, Wr, Wh, WtM, WtZR, WtH, nf, H, P0, N);

  const int mblk = (N + 63) / 64;
  const int g256 = (N + 7) / 8;     // 2 nodes/wave, 4 waves/block
  const int g128 = (N + 15) / 16;   // 4 nodes/wave

  // --- AP0 = Agg([nf|H]) ---
  if (small)
    gather<256, unsigned short><<<g256, 256, 0, stream>>>(P0, off, (const unsigned short*)eidx, AP0, N);
  else
    gather<256, int><<<g256, 256, 0, stream>>>(P0, off, (const int*)eidx, AP0, N);

  // --- X = relu(Anf @ Wm + bm) ---
  gemm_mfma<1, 0><<<dim3(mblk, 1), 256, 0, stream>>>(
      AP0, 256, nullptr, 0, WtM, bm, nullptr, nullptr, nullptr, X, nullptr, nullptr, N);

  // --- AX = Agg(X) ---
  if (small)
    gather<128, unsigned short><<<g128, 256, 0, stream>>>(X, off, (const unsigned short*)eidx, AX, N);
  else
    gather<128, int><<<g128, 256, 0, stream>>>(X, off, (const int*)eidx, AX, N);

  // --- Z = sig([AX,AH]@Wz+bz), G = sig([AX,AH]@Wr+br)*Hh ---
  gemm_mfma<2, 1><<<dim3(mblk, 2), 256, 0, stream>>>(
      AX, 128, AP0 + 128, 256, WtZR, bz, br, Hh, nullptr, Zh, G, nullptr, N);

  // --- AG = Agg(G) ---
  if (small)
    gather<128, unsigned short><<<g128, 256, 0, stream>>>(G, off, (const unsigned short*)eidx, AG, N);
  else
    gather<128, int><<<g128, 256, 0, stream>>>(G, off, (const int*)eidx, AG, N);

  // --- out = Zh*Hh + (1-Zh)*tanh([AX,AG]@Wh + bh) ---
  gemm_mfma<2, 2><<<dim3(mblk, 1), 256, 0, stream>>>(
      AX, 128, AG, 128, WtH, bh, nullptr, Hh, Zh, nullptr, nullptr, out, N);
}